// Round 1
// baseline (224.538 us; speedup 1.0000x reference)
//
#include <hip/hip_runtime.h>

typedef unsigned short u16;
typedef unsigned int u32;
typedef __attribute__((ext_vector_type(8))) __bf16 bf16x8;
typedef __attribute__((ext_vector_type(4))) float f32x4;

#define NB 4
#define SEQ 2048
#define DIM 512
#define NH 8
#define HD 64
#define OV 32
#define PD 2112
#define NW 32

__device__ __forceinline__ u16 f2bf(float f) {
  union { float f; u32 u; } x; x.f = f;
  u32 r = x.u + 0x7fffu + ((x.u >> 16) & 1u);
  return (u16)(r >> 16);
}
__device__ __forceinline__ float bf2f(u32 lo) {
  union { u32 u; float f; } x; x.u = lo << 16;
  return x.f;
}

// ---------------- prep kernels ----------------

// pack begin|main|end -> padded bf16 [NB*PD][DIM]
__global__ void k_pack_padded(const float* __restrict__ begin,
                              const float* __restrict__ mainp,
                              const float* __restrict__ endp,
                              u16* __restrict__ pad) {
  int i = blockIdx.x * 256 + threadIdx.x;     // over NB*PD*DIM/4 chunks
  if (i >= NB * PD * (DIM / 4)) return;
  int d4 = (i & 127) * 4;
  int p = (i >> 7) % PD;
  int b = i / (PD * (DIM / 4));
  const float* src;
  if (p < OV)            src = begin + ((size_t)(b * OV + p)) * DIM + d4;
  else if (p < OV + SEQ) src = mainp + ((size_t)(b * SEQ + (p - OV))) * DIM + d4;
  else                   src = endp + ((size_t)(b * OV + (p - OV - SEQ))) * DIM + d4;
  float4 v = *(const float4*)src;
  u32 lo = (u32)f2bf(v.x) | ((u32)f2bf(v.y) << 16);
  u32 hi = (u32)f2bf(v.z) | ((u32)f2bf(v.w) << 16);
  *(uint2*)&pad[(size_t)i * 4] = make_uint2(lo, hi);
}

__global__ void k_f32_to_bf16(const float* __restrict__ src, u16* __restrict__ dst, int n4) {
  int i = blockIdx.x * 256 + threadIdx.x;
  if (i >= n4) return;
  float4 v = *(const float4*)&src[(size_t)i * 4];
  u32 lo = (u32)f2bf(v.x) | ((u32)f2bf(v.y) << 16);
  u32 hi = (u32)f2bf(v.z) | ((u32)f2bf(v.w) << 16);
  *(uint2*)&dst[(size_t)i * 4] = make_uint2(lo, hi);
}

// ---------------- GEMM mainloop (128x128 tile, BK=32, 256 threads) ----------------
// A [M][512] bf16 K-major, Bw [N][512] bf16 K-major. acc[fm][fn] per wave (2x2 waves, 64x64/wave).

__device__ __forceinline__ void gemm_tile_128(const u16* __restrict__ A,
                                              const u16* __restrict__ Bw,
                                              int tm0, int tn0,
                                              u16 As[128][40], u16 Bs[128][40],
                                              f32x4 acc[4][4]) {
  const int tid = threadIdx.x;
  const int lane = tid & 63;
  const int wv = tid >> 6;
  const int wm = (wv >> 1) * 64, wn = (wv & 1) * 64;
  const int r0 = tid >> 2;
  const int sg = (tid & 3) * 8;
  const int rr = lane & 15;
  const int kk = (lane >> 4) * 8;
  for (int k0 = 0; k0 < 512; k0 += 32) {
    {
      int r1 = r0, r2 = r0 + 64;
      *(uint4*)&As[r1][sg] = *(const uint4*)&A[(size_t)(tm0 + r1) * 512 + k0 + sg];
      *(uint4*)&As[r2][sg] = *(const uint4*)&A[(size_t)(tm0 + r2) * 512 + k0 + sg];
      *(uint4*)&Bs[r1][sg] = *(const uint4*)&Bw[(size_t)(tn0 + r1) * 512 + k0 + sg];
      *(uint4*)&Bs[r2][sg] = *(const uint4*)&Bw[(size_t)(tn0 + r2) * 512 + k0 + sg];
    }
    __syncthreads();
    bf16x8 af[4], bfr[4];
#pragma unroll
    for (int f = 0; f < 4; ++f) {
      af[f] = *(const bf16x8*)&As[wm + f * 16 + rr][kk];
      bfr[f] = *(const bf16x8*)&Bs[wn + f * 16 + rr][kk];
    }
#pragma unroll
    for (int fm = 0; fm < 4; ++fm)
#pragma unroll
      for (int fn = 0; fn < 4; ++fn)
        acc[fm][fn] = __builtin_amdgcn_mfma_f32_16x16x32_bf16(af[fm], bfr[fn], acc[fm][fn], 0, 0, 0);
    __syncthreads();
  }
}

// QKV GEMM: M=8448 (NB*PD), N=1536. Scatter into head-major q/k/v bf16.
__global__ __launch_bounds__(256) void k_gemm_qkv(const u16* __restrict__ A,
                                                  const u16* __restrict__ Bw,
                                                  const float* __restrict__ bias,
                                                  u16* __restrict__ qh,
                                                  u16* __restrict__ kh,
                                                  u16* __restrict__ vh) {
  __shared__ __align__(16) u16 As[128][40];
  __shared__ __align__(16) u16 Bs[128][40];
  int bx = blockIdx.x;
  int tm0 = (bx / 12) * 128, tn0 = (bx % 12) * 128;
  f32x4 acc[4][4] = {};
  gemm_tile_128(A, Bw, tm0, tn0, As, Bs, acc);
  int lane = threadIdx.x & 63, wv = threadIdx.x >> 6;
  int wm = (wv >> 1) * 64, wn = (wv & 1) * 64;
#pragma unroll
  for (int fm = 0; fm < 4; ++fm)
#pragma unroll
    for (int fn = 0; fn < 4; ++fn) {
      int gcol = tn0 + wn + fn * 16 + (lane & 15);
      int reg = gcol >> 9, c = gcol & 511, h = c >> 6, d = c & 63;
      float bb = bias[gcol];
#pragma unroll
      for (int r = 0; r < 4; ++r) {
        int grow = tm0 + wm + fm * 16 + (lane >> 4) * 4 + r;
        int b = grow / PD, p = grow - b * PD;
        float v = acc[fm][fn][r] + bb;
        u16 u = f2bf(v);
        if (reg == 0) {
          if (p >= OV && p < OV + SEQ)
            qh[(((size_t)(b * NH + h)) * SEQ + (p - OV)) * HD + d] = u;
        } else if (reg == 1) {
          kh[(((size_t)(b * NH + h)) * PD + p) * HD + d] = u;
        } else {
          vh[(((size_t)(b * NH + h)) * PD + p) * HD + d] = u;
        }
      }
    }
}

// out-proj GEMM: M=8192, N=512, writes fp32 into out[:, 512:1024]
__global__ __launch_bounds__(256) void k_gemm_oproj(const u16* __restrict__ A,
                                                    const u16* __restrict__ Bw,
                                                    const float* __restrict__ bias,
                                                    float* __restrict__ out) {
  __shared__ __align__(16) u16 As[128][40];
  __shared__ __align__(16) u16 Bs[128][40];
  int bx = blockIdx.x;
  int tm0 = (bx / 4) * 128, tn0 = (bx % 4) * 128;
  f32x4 acc[4][4] = {};
  gemm_tile_128(A, Bw, tm0, tn0, As, Bs, acc);
  int lane = threadIdx.x & 63, wv = threadIdx.x >> 6;
  int wm = (wv >> 1) * 64, wn = (wv & 1) * 64;
#pragma unroll
  for (int fm = 0; fm < 4; ++fm)
#pragma unroll
    for (int fn = 0; fn < 4; ++fn) {
      int j = tn0 + wn + fn * 16 + (lane & 15);
      float bb = bias[j];
#pragma unroll
      for (int r = 0; r < 4; ++r) {
        int row = tm0 + wm + fm * 16 + (lane >> 4) * 4 + r;
        out[(size_t)row * 1024 + 512 + j] = acc[fm][fn][r] + bb;
      }
    }
}

// ---------------- attention ----------------
// one block per (b, h, 128-query tile); 128 threads, thread t owns query l0+t.
__global__ __launch_bounds__(128, 1) void k_attn(const u16* __restrict__ qh,
                                                 const u16* __restrict__ kh,
                                                 const u16* __restrict__ vh,
                                                 u16* __restrict__ ob) {
  __shared__ __align__(16) u16 kt[192][72];
  __shared__ __align__(16) u16 vt[192][72];
  int t = threadIdx.x;
  int bx = blockIdx.x;
  int tile = bx & 15, h = (bx >> 4) & 7, b = bx >> 7;
  int l0 = tile * 128;
  size_t base = (((size_t)(b * NH + h)) * PD + l0) * HD;
  const u16* kg = kh + base;
  const u16* vg = vh + base;
  for (int i = t; i < 192 * 8; i += 128) {
    int row = i >> 3, sg = (i & 7) * 8;
    *(uint4*)&kt[row][sg] = *(const uint4*)&kg[(size_t)row * HD + sg];
    *(uint4*)&vt[row][sg] = *(const uint4*)&vg[(size_t)row * HD + sg];
  }
  int l = l0 + t;
  const u16* qg = qh + (((size_t)(b * NH + h)) * SEQ + l) * HD;
  float qf[64];
#pragma unroll
  for (int i = 0; i < 16; ++i) {
    uint2 u = *(const uint2*)&qg[i * 4];
    qf[i * 4 + 0] = bf2f(u.x & 0xffffu);
    qf[i * 4 + 1] = bf2f(u.x >> 16);
    qf[i * 4 + 2] = bf2f(u.y & 0xffffu);
    qf[i * 4 + 3] = bf2f(u.y >> 16);
  }
  __syncthreads();
  float s[32];
#pragma unroll
  for (int w = 0; w < 32; ++w) {
    int row = t + ((w < 16) ? 2 * w : 2 * w + 2);
    float acc = 0.f;
#pragma unroll
    for (int sg = 0; sg < 8; ++sg) {
      uint4 kkv = *(const uint4*)&kt[row][sg * 8];
      acc += qf[sg * 8 + 0] * bf2f(kkv.x & 0xffffu) + qf[sg * 8 + 1] * bf2f(kkv.x >> 16);
      acc += qf[sg * 8 + 2] * bf2f(kkv.y & 0xffffu) + qf[sg * 8 + 3] * bf2f(kkv.y >> 16);
      acc += qf[sg * 8 + 4] * bf2f(kkv.z & 0xffffu) + qf[sg * 8 + 5] * bf2f(kkv.z >> 16);
      acc += qf[sg * 8 + 6] * bf2f(kkv.w & 0xffffu) + qf[sg * 8 + 7] * bf2f(kkv.w >> 16);
    }
    s[w] = acc * 0.125f;
  }
  float m = s[0];
#pragma unroll
  for (int w = 1; w < 32; ++w) m = fmaxf(m, s[w]);
  float sum = 0.f;
#pragma unroll
  for (int w = 0; w < 32; ++w) {
    s[w] = __expf(s[w] - m);
    sum += s[w];
  }
  float inv = 1.f / sum;
  float o[64];
#pragma unroll
  for (int i = 0; i < 64; ++i) o[i] = 0.f;
#pragma unroll
  for (int w = 0; w < 32; ++w) {
    int row = t + ((w < 16) ? 2 * w : 2 * w + 2);
    float p = s[w];
#pragma unroll
    for (int sg = 0; sg < 8; ++sg) {
      uint4 vv = *(const uint4*)&vt[row][sg * 8];
      o[sg * 8 + 0] += p * bf2f(vv.x & 0xffffu);
      o[sg * 8 + 1] += p * bf2f(vv.x >> 16);
      o[sg * 8 + 2] += p * bf2f(vv.y & 0xffffu);
      o[sg * 8 + 3] += p * bf2f(vv.y >> 16);
      o[sg * 8 + 4] += p * bf2f(vv.z & 0xffffu);
      o[sg * 8 + 5] += p * bf2f(vv.z >> 16);
      o[sg * 8 + 6] += p * bf2f(vv.w & 0xffffu);
      o[sg * 8 + 7] += p * bf2f(vv.w >> 16);
    }
  }
  u16* og = ob + ((size_t)(b * SEQ + l)) * DIM + h * HD;
#pragma unroll
  for (int i = 0; i < 32; ++i) {
    u32 pk = (u32)f2bf(o[2 * i] * inv) | ((u32)f2bf(o[2 * i + 1] * inv) << 16);
    ((u32*)og)[i] = pk;
  }
}

// copy main (fp32) into out[:, 0:512]
__global__ void k_copy_main(const float* __restrict__ mainp, float* __restrict__ out) {
  int i = blockIdx.x * 256 + threadIdx.x;  // over 8192*512/4 chunks
  if (i >= SEQ * NB * (DIM / 4)) return;
  int row = i >> 7;
  int c4 = (i & 127) * 4;
  *(float4*)&out[(size_t)row * 1024 + c4] = *(const float4*)&mainp[(size_t)i * 4];
}

extern "C" void kernel_launch(void* const* d_in, const int* in_sizes, int n_in,
                              void* d_out, int out_size, void* d_ws, size_t ws_size,
                              hipStream_t stream) {
  const float* begin = (const float*)d_in[0];
  const float* mainp = (const float*)d_in[1];
  const float* endp = (const float*)d_in[2];
  const float* w_in_f = (const float*)d_in[3];
  const float* b_in = (const float*)d_in[4];
  const float* w_out_f = (const float*)d_in[5];
  const float* b_out = (const float*)d_in[6];
  float* out = (float*)d_out;

  char* ws = (char*)d_ws;
  u16* pad_bf = (u16*)ws; ws += (size_t)NB * PD * DIM * 2;        // 8,650,752
  u16* w_in = (u16*)ws;   ws += (size_t)3 * DIM * DIM * 2;        // 1,572,864
  u16* w_out = (u16*)ws;  ws += (size_t)DIM * DIM * 2;            // 524,288
  u16* qhb = (u16*)ws;    ws += (size_t)NB * NH * SEQ * HD * 2;   // 8,388,608
  u16* khb = (u16*)ws;    ws += (size_t)NB * NH * PD * HD * 2;    // 8,650,752
  u16* vhb = (u16*)ws;    ws += (size_t)NB * NH * PD * HD * 2;    // 8,650,752
  u16* ob = (u16*)ws;     ws += (size_t)NB * SEQ * DIM * 2;       // 8,388,608

  // 1. pack padded input to bf16
  k_pack_padded<<<(NB * PD * (DIM / 4) + 255) / 256, 256, 0, stream>>>(begin, mainp, endp, pad_bf);
  // 2. convert weights
  k_f32_to_bf16<<<(3 * DIM * DIM / 4 + 255) / 256, 256, 0, stream>>>(w_in_f, w_in, 3 * DIM * DIM / 4);
  k_f32_to_bf16<<<(DIM * DIM / 4 + 255) / 256, 256, 0, stream>>>(w_out_f, w_out, DIM * DIM / 4);
  // 3. QKV projection GEMM (M=8448, N=1536, K=512)
  k_gemm_qkv<<<66 * 12, 256, 0, stream>>>(pad_bf, w_in, b_in, qhb, khb, vhb);
  // 4. windowed attention
  k_attn<<<NB * NH * (SEQ / 128), 128, 0, stream>>>(qhb, khb, vhb, ob);
  // 5. out projection GEMM (M=8192, N=512, K=512) -> out[:, 512:]
  k_gemm_oproj<<<64 * 4, 256, 0, stream>>>(ob, w_out, b_out, out);
  // 6. passthrough main -> out[:, :512]
  k_copy_main<<<(SEQ * NB * (DIM / 4) + 255) / 256, 256, 0, stream>>>(mainp, out);
}

// Round 2
// 83.049 us; speedup vs baseline: 2.7037x; 2.7037x over previous
//
#include <hip/hip_runtime.h>

typedef unsigned short u16;
typedef unsigned int u32;
typedef __attribute__((ext_vector_type(8))) __bf16 bf16x8;
typedef __attribute__((ext_vector_type(4))) float f32x4;

#define NB 4
#define SEQ 2048
#define DIM 512
#define NH 8
#define HD 64
#define OV 32
#define PD 2112

__device__ __forceinline__ u16 f2bf(float f) {
  union { float f; u32 u; } x; x.f = f;
  u32 r = x.u + 0x7fffu + ((x.u >> 16) & 1u);
  return (u16)(r >> 16);
}

// ---------------- prep kernels ----------------

__global__ void k_pack_padded(const float* __restrict__ begin,
                              const float* __restrict__ mainp,
                              const float* __restrict__ endp,
                              u16* __restrict__ pad) {
  int i = blockIdx.x * 256 + threadIdx.x;
  if (i >= NB * PD * (DIM / 4)) return;
  int d4 = (i & 127) * 4;
  int p = (i >> 7) % PD;
  int b = i / (PD * (DIM / 4));
  const float* src;
  if (p < OV)            src = begin + ((size_t)(b * OV + p)) * DIM + d4;
  else if (p < OV + SEQ) src = mainp + ((size_t)(b * SEQ + (p - OV))) * DIM + d4;
  else                   src = endp + ((size_t)(b * OV + (p - OV - SEQ))) * DIM + d4;
  float4 v = *(const float4*)src;
  u32 lo = (u32)f2bf(v.x) | ((u32)f2bf(v.y) << 16);
  u32 hi = (u32)f2bf(v.z) | ((u32)f2bf(v.w) << 16);
  *(uint2*)&pad[(size_t)i * 4] = make_uint2(lo, hi);
}

__global__ void k_f32_to_bf16(const float* __restrict__ src, u16* __restrict__ dst, int n4) {
  int i = blockIdx.x * 256 + threadIdx.x;
  if (i >= n4) return;
  float4 v = *(const float4*)&src[(size_t)i * 4];
  u32 lo = (u32)f2bf(v.x) | ((u32)f2bf(v.y) << 16);
  u32 hi = (u32)f2bf(v.z) | ((u32)f2bf(v.w) << 16);
  *(uint2*)&dst[(size_t)i * 4] = make_uint2(lo, hi);
}

// ---------------- GEMM mainloop (128x128 tile, BK=32, 256 threads) ----------------

__device__ __forceinline__ void gemm_tile_128(const u16* __restrict__ A,
                                              const u16* __restrict__ Bw,
                                              int tm0, int tn0,
                                              u16 As[128][40], u16 Bs[128][40],
                                              f32x4 acc[4][4]) {
  const int tid = threadIdx.x;
  const int lane = tid & 63;
  const int wv = tid >> 6;
  const int wm = (wv >> 1) * 64, wn = (wv & 1) * 64;
  const int r0 = tid >> 2;
  const int sg = (tid & 3) * 8;
  const int rr = lane & 15;
  const int kk = (lane >> 4) * 8;
  for (int k0 = 0; k0 < 512; k0 += 32) {
    {
      int r1 = r0, r2 = r0 + 64;
      *(uint4*)&As[r1][sg] = *(const uint4*)&A[(size_t)(tm0 + r1) * 512 + k0 + sg];
      *(uint4*)&As[r2][sg] = *(const uint4*)&A[(size_t)(tm0 + r2) * 512 + k0 + sg];
      *(uint4*)&Bs[r1][sg] = *(const uint4*)&Bw[(size_t)(tn0 + r1) * 512 + k0 + sg];
      *(uint4*)&Bs[r2][sg] = *(const uint4*)&Bw[(size_t)(tn0 + r2) * 512 + k0 + sg];
    }
    __syncthreads();
    bf16x8 af[4], bfr[4];
#pragma unroll
    for (int f = 0; f < 4; ++f) {
      af[f] = *(const bf16x8*)&As[wm + f * 16 + rr][kk];
      bfr[f] = *(const bf16x8*)&Bs[wn + f * 16 + rr][kk];
    }
#pragma unroll
    for (int fm = 0; fm < 4; ++fm)
#pragma unroll
      for (int fn = 0; fn < 4; ++fn)
        acc[fm][fn] = __builtin_amdgcn_mfma_f32_16x16x32_bf16(af[fm], bfr[fn], acc[fm][fn], 0, 0, 0);
    __syncthreads();
  }
}

// QKV GEMM: M=8448, N=1536. q,k head-major [p][d]; v TRANSPOSED head-major [d][p].
__global__ __launch_bounds__(256) void k_gemm_qkv(const u16* __restrict__ A,
                                                  const u16* __restrict__ Bw,
                                                  const float* __restrict__ bias,
                                                  u16* __restrict__ qh,
                                                  u16* __restrict__ kh,
                                                  u16* __restrict__ vt) {
  __shared__ __align__(16) u16 As[128][40];
  __shared__ __align__(16) u16 Bs[128][40];
  int bx = blockIdx.x;
  int tm0 = (bx / 12) * 128, tn0 = (bx % 12) * 128;
  f32x4 acc[4][4] = {};
  gemm_tile_128(A, Bw, tm0, tn0, As, Bs, acc);
  int lane = threadIdx.x & 63, wv = threadIdx.x >> 6;
  int wm = (wv >> 1) * 64, wn = (wv & 1) * 64;
#pragma unroll
  for (int fm = 0; fm < 4; ++fm)
#pragma unroll
    for (int fn = 0; fn < 4; ++fn) {
      int gcol = tn0 + wn + fn * 16 + (lane & 15);
      int reg = gcol >> 9, c = gcol & 511, h = c >> 6, d = c & 63;
      float bb = bias[gcol];
      int grow0 = tm0 + wm + fm * 16 + (lane >> 4) * 4;  // 4-aligned; PD%4==0 so quad stays in one b
      int b = grow0 / PD, p0 = grow0 - b * PD;
      if (reg == 2) {
        u16 u0 = f2bf(acc[fm][fn][0] + bb);
        u16 u1 = f2bf(acc[fm][fn][1] + bb);
        u16 u2 = f2bf(acc[fm][fn][2] + bb);
        u16 u3 = f2bf(acc[fm][fn][3] + bb);
        *(uint2*)&vt[(((size_t)(b * NH + h)) * HD + d) * PD + p0] =
            make_uint2((u32)u0 | ((u32)u1 << 16), (u32)u2 | ((u32)u3 << 16));
      } else if (reg == 1) {
#pragma unroll
        for (int r = 0; r < 4; ++r)
          kh[(((size_t)(b * NH + h)) * PD + p0 + r) * HD + d] = f2bf(acc[fm][fn][r] + bb);
      } else {
#pragma unroll
        for (int r = 0; r < 4; ++r) {
          int p = p0 + r;
          if (p >= OV && p < OV + SEQ)
            qh[(((size_t)(b * NH + h)) * SEQ + (p - OV)) * HD + d] = f2bf(acc[fm][fn][r] + bb);
        }
      }
    }
}

// out-proj GEMM: M=8192, N=512, fp32 into out[:, 512:1024]
__global__ __launch_bounds__(256) void k_gemm_oproj(const u16* __restrict__ A,
                                                    const u16* __restrict__ Bw,
                                                    const float* __restrict__ bias,
                                                    float* __restrict__ out) {
  __shared__ __align__(16) u16 As[128][40];
  __shared__ __align__(16) u16 Bs[128][40];
  int bx = blockIdx.x;
  int tm0 = (bx / 4) * 128, tn0 = (bx % 4) * 128;
  f32x4 acc[4][4] = {};
  gemm_tile_128(A, Bw, tm0, tn0, As, Bs, acc);
  int lane = threadIdx.x & 63, wv = threadIdx.x >> 6;
  int wm = (wv >> 1) * 64, wn = (wv & 1) * 64;
#pragma unroll
  for (int fm = 0; fm < 4; ++fm)
#pragma unroll
    for (int fn = 0; fn < 4; ++fn) {
      int j = tn0 + wn + fn * 16 + (lane & 15);
      float bb = bias[j];
#pragma unroll
      for (int r = 0; r < 4; ++r) {
        int row = tm0 + wm + fm * 16 + (lane >> 4) * 4 + r;
        out[(size_t)row * 1024 + 512 + j] = acc[fm][fn][r] + bb;
      }
    }
}

// ---------------- MFMA banded attention ----------------
// Block: 256 thr = 4 waves, 64 queries (16/wave). K/V padded rows [l0, l0+128).
// Swapped QK^T (S^T = K·Q^T) -> in-lane softmax -> P to swizzled LDS -> P·V^T(MFMA).

// Ps slot swizzle: slots 0..7 XOR 3-bit key, slots 8..11 XOR 2-bit key (stays in range).
__device__ __forceinline__ int pswz(int slot, int key) {
  return (slot < 8) ? (slot ^ (key & 7)) : ((slot & 12) | ((slot ^ (key & 3)) & 3));
}

__global__ __launch_bounds__(256) void k_attn(const u16* __restrict__ qh,
                                              const u16* __restrict__ kh,
                                              const u16* __restrict__ vt,
                                              u16* __restrict__ ob) {
  __shared__ __align__(16) u16 Ks[128 * 64];   // [row][slot^row&7][8]
  __shared__ __align__(16) u16 Vs[64 * 128];   // V^T: [d][slot^d&15][8]
  __shared__ __align__(16) u16 Qs[64 * 64];    // [row][slot^row&7][8]
  __shared__ __align__(16) u16 Ps[4 * 16 * 96];// per-wave [16 q][96 w], pswz slots
  const int tid = threadIdx.x;
  const int lane = tid & 63;
  const int wq = tid >> 6;
  const int g = lane >> 4, qi = lane & 15;
  const int bx = blockIdx.x;
  const int tile = bx & 31, h = (bx >> 5) & 7, b = bx >> 8;
  const int l0 = tile * 64;
  const size_t bh = (size_t)(b * NH + h);

  // ---- stage K / V^T / Q with 16B-slot XOR swizzle ----
  {
    const u16* kg = kh + (bh * PD + l0) * HD;
#pragma unroll
    for (int i = 0; i < 4; ++i) {
      int c = tid + 256 * i;                 // 0..1023
      int row = c >> 3, slot = c & 7;
      *(uint4*)&Ks[row * 64 + ((slot ^ (row & 7)) << 3)] =
          *(const uint4*)&kg[(size_t)row * HD + slot * 8];
    }
    const u16* vg = vt + bh * HD * PD + l0;
#pragma unroll
    for (int i = 0; i < 4; ++i) {
      int c = tid + 256 * i;                 // 0..1023
      int d = c >> 4, slot = c & 15;
      *(uint4*)&Vs[d * 128 + ((slot ^ (d & 15)) << 3)] =
          *(const uint4*)&vg[(size_t)d * PD + slot * 8];
    }
    const u16* qg = qh + (bh * SEQ + l0) * HD;
#pragma unroll
    for (int i = 0; i < 2; ++i) {
      int c = tid + 256 * i;                 // 0..511
      int row = c >> 3, slot = c & 7;
      *(uint4*)&Qs[row * 64 + ((slot ^ (row & 7)) << 3)] =
          *(const uint4*)&qg[(size_t)row * HD + slot * 8];
    }
  }
  __syncthreads();

  // ---- QK^T (swapped): wave wq covers j_loc in [16wq, 16wq+80) via 5 tiles ----
  bf16x8 bq[2];
  {
    int qrow = 16 * wq + qi;
#pragma unroll
    for (int ks = 0; ks < 2; ++ks)
      bq[ks] = *(const bf16x8*)&Qs[qrow * 64 + ((((g + 4 * ks)) ^ (qrow & 7)) << 3)];
  }
  f32x4 sa[5];
#pragma unroll
  for (int tt = 0; tt < 5; ++tt) { f32x4 z = {0.f, 0.f, 0.f, 0.f}; sa[tt] = z; }
#pragma unroll
  for (int tt = 0; tt < 5; ++tt) {
    int krow = 16 * (wq + tt) + qi;
#pragma unroll
    for (int ks = 0; ks < 2; ++ks) {
      bf16x8 ak = *(const bf16x8*)&Ks[krow * 64 + (((g + 4 * ks) ^ (krow & 7)) << 3)];
      sa[tt] = __builtin_amdgcn_mfma_f32_16x16x32_bf16(ak, bq[ks], sa[tt], 0, 0, 0);
    }
  }

  // ---- masked softmax (scale folded into exp); row = query qi, spread over 4 lanes ----
  float m = -1e30f;
#pragma unroll
  for (int tt = 0; tt < 5; ++tt)
#pragma unroll
    for (int r = 0; r < 4; ++r) {
      int rel = 16 * tt + 4 * g + r - qi;
      bool val = (rel >= 0) && (rel <= 64) && (rel != 32) && ((rel & 1) == 0);
      if (val) m = fmaxf(m, sa[tt][r]);
    }
  m = fmaxf(m, __shfl_xor(m, 16));
  m = fmaxf(m, __shfl_xor(m, 32));
  float p[5][4];
  float sum = 0.f;
#pragma unroll
  for (int tt = 0; tt < 5; ++tt)
#pragma unroll
    for (int r = 0; r < 4; ++r) {
      int rel = 16 * tt + 4 * g + r - qi;
      bool val = (rel >= 0) && (rel <= 64) && (rel != 32) && ((rel & 1) == 0);
      p[tt][r] = val ? __expf((sa[tt][r] - m) * 0.125f) : 0.f;
      sum += p[tt][r];
    }
  sum += __shfl_xor(sum, 16);
  sum += __shfl_xor(sum, 32);
  float inv = 1.f / sum;

  // ---- write normalized P (bf16) to per-wave Ps; col = j_abs - 32*(wq>=2) ----
  {
    int prow = 16 * wq + qi;
    int colb = (wq & 1) << 4;
#pragma unroll
    for (int tt = 0; tt < 5; ++tt) {
#pragma unroll
      for (int pp = 0; pp < 2; ++pp) {
        int e = 4 * g + 2 * pp;                       // even offset within 16-col group
        int slot = ((colb + 16 * tt) >> 3) + (e >> 3);
        int swz = pswz(slot, qi);
        u32 w = (u32)f2bf(p[tt][2 * pp] * inv) | ((u32)f2bf(p[tt][2 * pp + 1] * inv) << 16);
        *(u32*)&Ps[prow * 96 + swz * 8 + (e & 7)] = w;
      }
    }
    // zero dead 16 columns (slots {10,11} for even wq, {0,1} for odd)
    int zslot = ((wq & 1) ? 0 : 10) + ((lane >> 4) & 1);
    int half = lane >> 5;
    int swz = pswz(zslot, qi);
    uint2 z2 = make_uint2(0u, 0u);
    *(uint2*)&Ps[(16 * wq + qi) * 96 + swz * 8 + half * 4] = z2;
  }
  __syncthreads();

  // ---- P·V: O[q][d], w-blocks absolute {0,1,2}+ (wq>=2) ----
  f32x4 oa[4];
#pragma unroll
  for (int dt = 0; dt < 4; ++dt) { f32x4 z = {0.f, 0.f, 0.f, 0.f}; oa[dt] = z; }
  int kbo = (wq >= 2) ? 1 : 0;
#pragma unroll
  for (int kt = 0; kt < 3; ++kt) {
    int slot = 4 * kt + g;
    int swz = pswz(slot, qi);
    bf16x8 pa = *(const bf16x8*)&Ps[(16 * wq + qi) * 96 + swz * 8];
    int sabs = 4 * (kt + kbo) + g;
#pragma unroll
    for (int dt = 0; dt < 4; ++dt) {
      int d = 16 * dt + qi;
      bf16x8 bv = *(const bf16x8*)&Vs[d * 128 + ((sabs ^ (d & 15)) << 3)];
      oa[dt] = __builtin_amdgcn_mfma_f32_16x16x32_bf16(pa, bv, oa[dt], 0, 0, 0);
    }
  }

  // ---- epilogue: C[row=q_out][col=d] ----
  u16* og = ob + ((size_t)b * SEQ + l0 + 16 * wq) * DIM + h * HD;
#pragma unroll
  for (int dt = 0; dt < 4; ++dt)
#pragma unroll
    for (int r = 0; r < 4; ++r) {
      int qo = 4 * g + r;
      og[(size_t)qo * DIM + 16 * dt + qi] = f2bf(oa[dt][r]);
    }
}

// copy main (fp32) into out[:, 0:512]
__global__ void k_copy_main(const float* __restrict__ mainp, float* __restrict__ out) {
  int i = blockIdx.x * 256 + threadIdx.x;
  if (i >= SEQ * NB * (DIM / 4)) return;
  int row = i >> 7;
  int c4 = (i & 127) * 4;
  *(float4*)&out[(size_t)row * 1024 + c4] = *(const float4*)&mainp[(size_t)i * 4];
}

extern "C" void kernel_launch(void* const* d_in, const int* in_sizes, int n_in,
                              void* d_out, int out_size, void* d_ws, size_t ws_size,
                              hipStream_t stream) {
  const float* begin = (const float*)d_in[0];
  const float* mainp = (const float*)d_in[1];
  const float* endp = (const float*)d_in[2];
  const float* w_in_f = (const float*)d_in[3];
  const float* b_in = (const float*)d_in[4];
  const float* w_out_f = (const float*)d_in[5];
  const float* b_out = (const float*)d_in[6];
  float* out = (float*)d_out;

  char* ws = (char*)d_ws;
  u16* pad_bf = (u16*)ws; ws += (size_t)NB * PD * DIM * 2;
  u16* w_in = (u16*)ws;   ws += (size_t)3 * DIM * DIM * 2;
  u16* w_out = (u16*)ws;  ws += (size_t)DIM * DIM * 2;
  u16* qhb = (u16*)ws;    ws += (size_t)NB * NH * SEQ * HD * 2;
  u16* khb = (u16*)ws;    ws += (size_t)NB * NH * PD * HD * 2;
  u16* vtb = (u16*)ws;    ws += (size_t)NB * NH * HD * PD * 2;   // transposed V
  u16* ob = (u16*)ws;     ws += (size_t)NB * SEQ * DIM * 2;

  k_pack_padded<<<(NB * PD * (DIM / 4) + 255) / 256, 256, 0, stream>>>(begin, mainp, endp, pad_bf);
  k_f32_to_bf16<<<(3 * DIM * DIM / 4 + 255) / 256, 256, 0, stream>>>(w_in_f, w_in, 3 * DIM * DIM / 4);
  k_f32_to_bf16<<<(DIM * DIM / 4 + 255) / 256, 256, 0, stream>>>(w_out_f, w_out, DIM * DIM / 4);
  k_gemm_qkv<<<66 * 12, 256, 0, stream>>>(pad_bf, w_in, b_in, qhb, khb, vtb);
  k_attn<<<NB * NH * (SEQ / 64), 256, 0, stream>>>(qhb, khb, vtb, ob);
  k_gemm_oproj<<<64 * 4, 256, 0, stream>>>(ob, w_out, b_out, out);
  k_copy_main<<<(SEQ * NB * (DIM / 4) + 255) / 256, 256, 0, stream>>>(mainp, out);
}

// Round 3
// 77.641 us; speedup vs baseline: 2.8920x; 1.0697x over previous
//
#include <hip/hip_runtime.h>

typedef unsigned short u16;
typedef unsigned int u32;
typedef __attribute__((ext_vector_type(8))) __bf16 bf16x8;
typedef __attribute__((ext_vector_type(4))) float f32x4;

#define NB 4
#define SEQ 2048
#define DIM 512
#define NH 8
#define HD 64
#define OV 32
#define PD 2112

#define PACK_N (NB * PD * (DIM / 4))
#define WIN_N (3 * DIM * DIM / 4)
#define WOUT_N (DIM * DIM / 4)

// async global->LDS, 16B per lane, wave-uniform LDS base + lane*16
#define GLL(g, l)                                                  \
  __builtin_amdgcn_global_load_lds(                                \
      (const __attribute__((address_space(1))) void*)(g),          \
      (__attribute__((address_space(3))) void*)(l), 16, 0, 0)

__device__ __forceinline__ u16 f2bf(float f) {
  union { float f; u32 u; } x; x.f = f;
  u32 r = x.u + 0x7fffu + ((x.u >> 16) & 1u);
  return (u16)(r >> 16);
}

// ---------------- fused prep: pack padded bf16 + convert both weights ----------------
__global__ void k_prep(const float* __restrict__ begin,
                       const float* __restrict__ mainp,
                       const float* __restrict__ endp,
                       const float* __restrict__ w_in_f,
                       const float* __restrict__ w_out_f,
                       u16* __restrict__ pad,
                       u16* __restrict__ w_in,
                       u16* __restrict__ w_out) {
  int i = blockIdx.x * 256 + threadIdx.x;
  const float* src;
  u16* dst;
  if (i < PACK_N) {
    int d4 = (i & 127) * 4;
    int p = (i >> 7) % PD;
    int b = i / (PD * (DIM / 4));
    if (p < OV)            src = begin + ((size_t)(b * OV + p)) * DIM + d4;
    else if (p < OV + SEQ) src = mainp + ((size_t)(b * SEQ + (p - OV))) * DIM + d4;
    else                   src = endp + ((size_t)(b * OV + (p - OV - SEQ))) * DIM + d4;
    dst = pad + (size_t)i * 4;
  } else if (i < PACK_N + WIN_N) {
    int j = i - PACK_N;
    src = w_in_f + (size_t)j * 4;
    dst = w_in + (size_t)j * 4;
  } else if (i < PACK_N + WIN_N + WOUT_N) {
    int j = i - PACK_N - WIN_N;
    src = w_out_f + (size_t)j * 4;
    dst = w_out + (size_t)j * 4;
  } else {
    return;
  }
  float4 v = *(const float4*)src;
  u32 lo = (u32)f2bf(v.x) | ((u32)f2bf(v.y) << 16);
  u32 hi = (u32)f2bf(v.z) | ((u32)f2bf(v.w) << 16);
  *(uint2*)dst = make_uint2(lo, hi);
}

// ---------------- GEMM mainloop: 128x128 tile, BK=32, global_load_lds + 2-phase dbuf ----
// A [M][512], Bw [N][512] bf16 K-major. LDS linear [2][128][32]. 256 thr = 4 waves (2x2).

__device__ __forceinline__ void gemm_loop(const u16* __restrict__ A,
                                          const u16* __restrict__ Bw,
                                          int tm0, int tn0,
                                          u16* As, u16* Bs,  // each [2][128*32]
                                          f32x4 acc[4][4]) {
  const int tid = threadIdx.x;
  const int lane = tid & 63;
  const int w = tid >> 6;
  const int rr = lane & 15;
  const int kb = (lane >> 4) * 8;
  const int wm = (w >> 1) * 64, wn = (w & 1) * 64;
  // staging: wave w covers rows [w*32, w*32+16) at issue 0, +16 rows at issue 1.
  // lane -> row w*32 + lane/4, k elems (lane&3)*8
  const u16* gA = A + (size_t)(tm0 + w * 32 + (lane >> 2)) * 512 + (lane & 3) * 8;
  const u16* gB = Bw + (size_t)(tn0 + w * 32 + (lane >> 2)) * 512 + (lane & 3) * 8;
  char* lA = (char*)As + w * 2048;  // wave-uniform
  char* lB = (char*)Bs + w * 2048;

  // prologue: stage k-step 0 into buffer 0
  GLL(gA, lA); GLL(gA + 16 * 512, lA + 1024);
  GLL(gB, lB); GLL(gB + 16 * 512, lB + 1024);
  __syncthreads();

#pragma unroll
  for (int t = 0; t < 16; ++t) {
    const int cur = t & 1;
    if (t < 15) {
      const int nxt = cur ^ 1;
      const u16* ga = gA + (t + 1) * 32;
      const u16* gb = gB + (t + 1) * 32;
      GLL(ga, lA + nxt * 8192); GLL(ga + 16 * 512, lA + nxt * 8192 + 1024);
      GLL(gb, lB + nxt * 8192); GLL(gb + 16 * 512, lB + nxt * 8192 + 1024);
    }
    const u16* cA = As + cur * 4096;
    const u16* cB = Bs + cur * 4096;
    bf16x8 af[4], bfr[4];
#pragma unroll
    for (int f = 0; f < 4; ++f) {
      af[f] = *(const bf16x8*)&cA[(wm + f * 16 + rr) * 32 + kb];
      bfr[f] = *(const bf16x8*)&cB[(wn + f * 16 + rr) * 32 + kb];
    }
#pragma unroll
    for (int fm = 0; fm < 4; ++fm)
#pragma unroll
      for (int fn = 0; fn < 4; ++fn)
        acc[fm][fn] = __builtin_amdgcn_mfma_f32_16x16x32_bf16(af[fm], bfr[fn], acc[fm][fn], 0, 0, 0);
    if (t < 15) __syncthreads();
  }
}

// QKV GEMM: M=8448, N=1536. q,k head-major [p][d]; v transposed head-major [d][p].
__global__ __launch_bounds__(256) void k_gemm_qkv(const u16* __restrict__ A,
                                                  const u16* __restrict__ Bw,
                                                  const float* __restrict__ bias,
                                                  u16* __restrict__ qh,
                                                  u16* __restrict__ kh,
                                                  u16* __restrict__ vt) {
  __shared__ __align__(16) u16 As[2][128][32];
  __shared__ __align__(16) u16 Bs[2][128][32];
  int bx = blockIdx.x;
  int tm0 = (bx / 12) * 128, tn0 = (bx % 12) * 128;
  f32x4 acc[4][4] = {};
  gemm_loop(A, Bw, tm0, tn0, &As[0][0][0], &Bs[0][0][0], acc);
  int lane = threadIdx.x & 63, wv = threadIdx.x >> 6;
  int wm = (wv >> 1) * 64, wn = (wv & 1) * 64;
#pragma unroll
  for (int fm = 0; fm < 4; ++fm)
#pragma unroll
    for (int fn = 0; fn < 4; ++fn) {
      int gcol = tn0 + wn + fn * 16 + (lane & 15);
      int reg = gcol >> 9, c = gcol & 511, h = c >> 6, d = c & 63;
      float bb = bias[gcol];
      int grow0 = tm0 + wm + fm * 16 + (lane >> 4) * 4;  // 4-aligned; PD%4==0
      int b = grow0 / PD, p0 = grow0 - b * PD;
      if (reg == 2) {
        u16 u0 = f2bf(acc[fm][fn][0] + bb);
        u16 u1 = f2bf(acc[fm][fn][1] + bb);
        u16 u2 = f2bf(acc[fm][fn][2] + bb);
        u16 u3 = f2bf(acc[fm][fn][3] + bb);
        *(uint2*)&vt[(((size_t)(b * NH + h)) * HD + d) * PD + p0] =
            make_uint2((u32)u0 | ((u32)u1 << 16), (u32)u2 | ((u32)u3 << 16));
      } else if (reg == 1) {
#pragma unroll
        for (int r = 0; r < 4; ++r)
          kh[(((size_t)(b * NH + h)) * PD + p0 + r) * HD + d] = f2bf(acc[fm][fn][r] + bb);
      } else {
#pragma unroll
        for (int r = 0; r < 4; ++r) {
          int p = p0 + r;
          if (p >= OV && p < OV + SEQ)
            qh[(((size_t)(b * NH + h)) * SEQ + (p - OV)) * HD + d] = f2bf(acc[fm][fn][r] + bb);
        }
      }
    }
}

// out-proj GEMM: M=8192, N=512 -> out[:,512:1024] fp32; fused main passthrough -> out[:,0:512]
__global__ __launch_bounds__(256) void k_gemm_oproj(const u16* __restrict__ A,
                                                    const u16* __restrict__ Bw,
                                                    const float* __restrict__ bias,
                                                    const float* __restrict__ mainp,
                                                    float* __restrict__ out) {
  __shared__ __align__(16) u16 As[2][128][32];
  __shared__ __align__(16) u16 Bs[2][128][32];
  int bx = blockIdx.x;
  int tm0 = (bx >> 2) * 128, tn0 = (bx & 3) * 128;
  // fused passthrough: rows [tm0,tm0+128), cols [tn0,tn0+128) of main -> out[:,0:512]
  for (int i = threadIdx.x; i < 4096; i += 256) {
    int r = i >> 5, c4 = (i & 31) * 4;
    *(float4*)&out[(size_t)(tm0 + r) * 1024 + tn0 + c4] =
        *(const float4*)&mainp[(size_t)(tm0 + r) * 512 + tn0 + c4];
  }
  f32x4 acc[4][4] = {};
  gemm_loop(A, Bw, tm0, tn0, &As[0][0][0], &Bs[0][0][0], acc);
  int lane = threadIdx.x & 63, wv = threadIdx.x >> 6;
  int wm = (wv >> 1) * 64, wn = (wv & 1) * 64;
#pragma unroll
  for (int fm = 0; fm < 4; ++fm)
#pragma unroll
    for (int fn = 0; fn < 4; ++fn) {
      int j = tn0 + wn + fn * 16 + (lane & 15);
      float bb = bias[j];
#pragma unroll
      for (int r = 0; r < 4; ++r) {
        int row = tm0 + wm + fm * 16 + (lane >> 4) * 4 + r;
        out[(size_t)row * 1024 + 512 + j] = acc[fm][fn][r] + bb;
      }
    }
}

// ---------------- MFMA banded attention (unchanged from round 2) ----------------
__device__ __forceinline__ int pswz(int slot, int key) {
  return (slot < 8) ? (slot ^ (key & 7)) : ((slot & 12) | ((slot ^ (key & 3)) & 3));
}

__global__ __launch_bounds__(256) void k_attn(const u16* __restrict__ qh,
                                              const u16* __restrict__ kh,
                                              const u16* __restrict__ vt,
                                              u16* __restrict__ ob) {
  __shared__ __align__(16) u16 Ks[128 * 64];
  __shared__ __align__(16) u16 Vs[64 * 128];
  __shared__ __align__(16) u16 Qs[64 * 64];
  __shared__ __align__(16) u16 Ps[4 * 16 * 96];
  const int tid = threadIdx.x;
  const int lane = tid & 63;
  const int wq = tid >> 6;
  const int g = lane >> 4, qi = lane & 15;
  const int bx = blockIdx.x;
  const int tile = bx & 31, h = (bx >> 5) & 7, b = bx >> 8;
  const int l0 = tile * 64;
  const size_t bh = (size_t)(b * NH + h);

  {
    const u16* kg = kh + (bh * PD + l0) * HD;
#pragma unroll
    for (int i = 0; i < 4; ++i) {
      int c = tid + 256 * i;
      int row = c >> 3, slot = c & 7;
      *(uint4*)&Ks[row * 64 + ((slot ^ (row & 7)) << 3)] =
          *(const uint4*)&kg[(size_t)row * HD + slot * 8];
    }
    const u16* vg = vt + bh * HD * PD + l0;
#pragma unroll
    for (int i = 0; i < 4; ++i) {
      int c = tid + 256 * i;
      int d = c >> 4, slot = c & 15;
      *(uint4*)&Vs[d * 128 + ((slot ^ (d & 15)) << 3)] =
          *(const uint4*)&vg[(size_t)d * PD + slot * 8];
    }
    const u16* qg = qh + (bh * SEQ + l0) * HD;
#pragma unroll
    for (int i = 0; i < 2; ++i) {
      int c = tid + 256 * i;
      int row = c >> 3, slot = c & 7;
      *(uint4*)&Qs[row * 64 + ((slot ^ (row & 7)) << 3)] =
          *(const uint4*)&qg[(size_t)row * HD + slot * 8];
    }
  }
  __syncthreads();

  bf16x8 bq[2];
  {
    int qrow = 16 * wq + qi;
#pragma unroll
    for (int ks = 0; ks < 2; ++ks)
      bq[ks] = *(const bf16x8*)&Qs[qrow * 64 + ((((g + 4 * ks)) ^ (qrow & 7)) << 3)];
  }
  f32x4 sa[5];
#pragma unroll
  for (int tt = 0; tt < 5; ++tt) { f32x4 z = {0.f, 0.f, 0.f, 0.f}; sa[tt] = z; }
#pragma unroll
  for (int tt = 0; tt < 5; ++tt) {
    int krow = 16 * (wq + tt) + qi;
#pragma unroll
    for (int ks = 0; ks < 2; ++ks) {
      bf16x8 ak = *(const bf16x8*)&Ks[krow * 64 + (((g + 4 * ks) ^ (krow & 7)) << 3)];
      sa[tt] = __builtin_amdgcn_mfma_f32_16x16x32_bf16(ak, bq[ks], sa[tt], 0, 0, 0);
    }
  }

  float m = -1e30f;
#pragma unroll
  for (int tt = 0; tt < 5; ++tt)
#pragma unroll
    for (int r = 0; r < 4; ++r) {
      int rel = 16 * tt + 4 * g + r - qi;
      bool val = (rel >= 0) && (rel <= 64) && (rel != 32) && ((rel & 1) == 0);
      if (val) m = fmaxf(m, sa[tt][r]);
    }
  m = fmaxf(m, __shfl_xor(m, 16));
  m = fmaxf(m, __shfl_xor(m, 32));
  float p[5][4];
  float sum = 0.f;
#pragma unroll
  for (int tt = 0; tt < 5; ++tt)
#pragma unroll
    for (int r = 0; r < 4; ++r) {
      int rel = 16 * tt + 4 * g + r - qi;
      bool val = (rel >= 0) && (rel <= 64) && (rel != 32) && ((rel & 1) == 0);
      p[tt][r] = val ? __expf((sa[tt][r] - m) * 0.125f) : 0.f;
      sum += p[tt][r];
    }
  sum += __shfl_xor(sum, 16);
  sum += __shfl_xor(sum, 32);
  float inv = 1.f / sum;

  {
    int prow = 16 * wq + qi;
    int colb = (wq & 1) << 4;
#pragma unroll
    for (int tt = 0; tt < 5; ++tt) {
#pragma unroll
      for (int pp = 0; pp < 2; ++pp) {
        int e = 4 * g + 2 * pp;
        int slot = ((colb + 16 * tt) >> 3) + (e >> 3);
        int swz = pswz(slot, qi);
        u32 w = (u32)f2bf(p[tt][2 * pp] * inv) | ((u32)f2bf(p[tt][2 * pp + 1] * inv) << 16);
        *(u32*)&Ps[prow * 96 + swz * 8 + (e & 7)] = w;
      }
    }
    int zslot = ((wq & 1) ? 0 : 10) + ((lane >> 4) & 1);
    int half = lane >> 5;
    int swz = pswz(zslot, qi);
    uint2 z2 = make_uint2(0u, 0u);
    *(uint2*)&Ps[(16 * wq + qi) * 96 + swz * 8 + half * 4] = z2;
  }
  __syncthreads();

  f32x4 oa[4];
#pragma unroll
  for (int dt = 0; dt < 4; ++dt) { f32x4 z = {0.f, 0.f, 0.f, 0.f}; oa[dt] = z; }
  int kbo = (wq >= 2) ? 1 : 0;
#pragma unroll
  for (int kt = 0; kt < 3; ++kt) {
    int slot = 4 * kt + g;
    int swz = pswz(slot, qi);
    bf16x8 pa = *(const bf16x8*)&Ps[(16 * wq + qi) * 96 + swz * 8];
    int sabs = 4 * (kt + kbo) + g;
#pragma unroll
    for (int dt = 0; dt < 4; ++dt) {
      int d = 16 * dt + qi;
      bf16x8 bv = *(const bf16x8*)&Vs[d * 128 + ((sabs ^ (d & 15)) << 3)];
      oa[dt] = __builtin_amdgcn_mfma_f32_16x16x32_bf16(pa, bv, oa[dt], 0, 0, 0);
    }
  }

  u16* og = ob + ((size_t)b * SEQ + l0 + 16 * wq) * DIM + h * HD;
#pragma unroll
  for (int dt = 0; dt < 4; ++dt)
#pragma unroll
    for (int r = 0; r < 4; ++r) {
      int qo = 4 * g + r;
      og[(size_t)qo * DIM + 16 * dt + qi] = f2bf(oa[dt][r]);
    }
}

extern "C" void kernel_launch(void* const* d_in, const int* in_sizes, int n_in,
                              void* d_out, int out_size, void* d_ws, size_t ws_size,
                              hipStream_t stream) {
  const float* begin = (const float*)d_in[0];
  const float* mainp = (const float*)d_in[1];
  const float* endp = (const float*)d_in[2];
  const float* w_in_f = (const float*)d_in[3];
  const float* b_in = (const float*)d_in[4];
  const float* w_out_f = (const float*)d_in[5];
  const float* b_out = (const float*)d_in[6];
  float* out = (float*)d_out;

  char* ws = (char*)d_ws;
  u16* pad_bf = (u16*)ws; ws += (size_t)NB * PD * DIM * 2;
  u16* w_in = (u16*)ws;   ws += (size_t)3 * DIM * DIM * 2;
  u16* w_out = (u16*)ws;  ws += (size_t)DIM * DIM * 2;
  u16* qhb = (u16*)ws;    ws += (size_t)NB * NH * SEQ * HD * 2;
  u16* khb = (u16*)ws;    ws += (size_t)NB * NH * PD * HD * 2;
  u16* vtb = (u16*)ws;    ws += (size_t)NB * NH * HD * PD * 2;
  u16* ob = (u16*)ws;     ws += (size_t)NB * SEQ * DIM * 2;

  k_prep<<<(PACK_N + WIN_N + WOUT_N + 255) / 256, 256, 0, stream>>>(
      begin, mainp, endp, w_in_f, w_out_f, pad_bf, w_in, w_out);
  k_gemm_qkv<<<66 * 12, 256, 0, stream>>>(pad_bf, w_in, b_in, qhb, khb, vtb);
  k_attn<<<NB * NH * (SEQ / 64), 256, 0, stream>>>(qhb, khb, vtb, ob);
  k_gemm_oproj<<<64 * 4, 256, 0, stream>>>(ob, w_out, b_out, mainp, out);
}

// Round 4
// 70.410 us; speedup vs baseline: 3.1890x; 1.1027x over previous
//
#include <hip/hip_runtime.h>

typedef unsigned short u16;
typedef unsigned int u32;
typedef __attribute__((ext_vector_type(8))) __bf16 bf16x8;
typedef __attribute__((ext_vector_type(4))) float f32x4;

#define NB 4
#define SEQ 2048
#define DIM 512
#define NH 8
#define HD 64
#define OV 32
#define PD 2112

#define PACK_N (NB * PD * (DIM / 4))
#define WIN_N (3 * DIM * DIM / 4)
#define WOUT_N (DIM * DIM / 4)

// async global->LDS, 16B per lane, wave-uniform LDS base + lane*16
#define GLL(g, l)                                                  \
  __builtin_amdgcn_global_load_lds(                                \
      (const __attribute__((address_space(1))) void*)(g),          \
      (__attribute__((address_space(3))) void*)(l), 16, 0, 0)

__device__ __forceinline__ u16 f2bf(float f) {
  union { float f; u32 u; } x; x.f = f;
  u32 r = x.u + 0x7fffu + ((x.u >> 16) & 1u);
  return (u16)(r >> 16);
}

// ---------------- fused prep ----------------
__global__ void k_prep(const float* __restrict__ begin,
                       const float* __restrict__ mainp,
                       const float* __restrict__ endp,
                       const float* __restrict__ w_in_f,
                       const float* __restrict__ w_out_f,
                       u16* __restrict__ pad,
                       u16* __restrict__ w_in,
                       u16* __restrict__ w_out) {
  int i = blockIdx.x * 256 + threadIdx.x;
  const float* src;
  u16* dst;
  if (i < PACK_N) {
    int d4 = (i & 127) * 4;
    int p = (i >> 7) % PD;
    int b = i / (PD * (DIM / 4));
    if (p < OV)            src = begin + ((size_t)(b * OV + p)) * DIM + d4;
    else if (p < OV + SEQ) src = mainp + ((size_t)(b * SEQ + (p - OV))) * DIM + d4;
    else                   src = endp + ((size_t)(b * OV + (p - OV - SEQ))) * DIM + d4;
    dst = pad + (size_t)i * 4;
  } else if (i < PACK_N + WIN_N) {
    int j = i - PACK_N;
    src = w_in_f + (size_t)j * 4;
    dst = w_in + (size_t)j * 4;
  } else if (i < PACK_N + WIN_N + WOUT_N) {
    int j = i - PACK_N - WIN_N;
    src = w_out_f + (size_t)j * 4;
    dst = w_out + (size_t)j * 4;
  } else {
    return;
  }
  float4 v = *(const float4*)src;
  u32 lo = (u32)f2bf(v.x) | ((u32)f2bf(v.y) << 16);
  u32 hi = (u32)f2bf(v.z) | ((u32)f2bf(v.w) << 16);
  *(uint2*)dst = make_uint2(lo, hi);
}

// ================= QKV GEMM: 256x256 tile, BK=64, 8 waves, counted-vmcnt pipeline =====
// A [8448][512], Bw [1536][512] bf16. LDS [2buf][A,B][256][64] linear, K-granule
// swizzle g^=(row&7) applied on global src (stage) and ds_read addr.

__global__ __launch_bounds__(512, 2) void k_gemm_qkv(const u16* __restrict__ A,
                                                     const u16* __restrict__ Bw,
                                                     const float* __restrict__ bias,
                                                     u16* __restrict__ qh,
                                                     u16* __restrict__ kh,
                                                     u16* __restrict__ vt) {
  __shared__ __align__(16) u16 lds[2][2][256 * 64];  // 128 KB
  const int tid = threadIdx.x;
  const int lane = tid & 63;
  const int wid = tid >> 6;
  const int wr = wid >> 2, wc = wid & 3;
  const int rr = lane & 15, g = lane >> 4;

  // bijective XCD grouping over 198 blocks (q=24, r=6): same-M tiles share an XCD
  int bx = blockIdx.x;
  int xcd = bx & 7, idx = bx >> 3;
  int g2 = (xcd < 6) ? (xcd * 25 + idx) : (150 + (xcd - 6) * 24 + idx);
  const int tm0 = (g2 / 6) * 256, tn0 = (g2 % 6) * 256;

  // staging addresses: issue i covers rows i*64 + (tid>>3); phys granule tid&7 holds
  // logical granule (tid&7)^(row&7); row&7 == (tid>>3)&7 independent of i.
  const int srow = tid >> 3;
  const int lg = (tid & 7) ^ (srow & 7);
  const u16* gAb = A + (size_t)(tm0 + srow) * 512 + lg * 8;
  const u16* gBb = Bw + (size_t)(tn0 + srow) * 512 + lg * 8;

#define STAGE(buf, kt) do {                                        \
    const u16* ga_ = gAb + (kt) * 64;                              \
    const u16* gb_ = gBb + (kt) * 64;                              \
    char* la_ = (char*)&lds[buf][0][0] + wid * 1024;               \
    char* lb_ = (char*)&lds[buf][1][0] + wid * 1024;               \
    GLL(ga_,             la_);                                     \
    GLL(ga_ + 64 * 512,  la_ + 8192);                              \
    GLL(ga_ + 128 * 512, la_ + 16384);                             \
    GLL(ga_ + 192 * 512, la_ + 24576);                             \
    GLL(gb_,             lb_);                                     \
    GLL(gb_ + 64 * 512,  lb_ + 8192);                              \
    GLL(gb_ + 128 * 512, lb_ + 16384);                             \
    GLL(gb_ + 192 * 512, lb_ + 24576);                             \
  } while (0)

  f32x4 acc[8][4] = {};

  STAGE(0, 0);
  STAGE(1, 1);
  asm volatile("s_waitcnt vmcnt(8)" ::: "memory");
  __builtin_amdgcn_s_barrier();

#pragma unroll
  for (int t = 0; t < 8; ++t) {
    const int cur = t & 1;
    const u16* la = &lds[cur][0][0];
    const u16* lb = &lds[cur][1][0];
    bf16x8 a0[8], a1[8], b0[4], b1[4];
#pragma unroll
    for (int fm = 0; fm < 8; ++fm) {
      int row = wr * 128 + fm * 16 + rr;
      a0[fm] = *(const bf16x8*)&la[row * 64 + ((g ^ (row & 7)) << 3)];
      a1[fm] = *(const bf16x8*)&la[row * 64 + (((4 + g) ^ (row & 7)) << 3)];
    }
#pragma unroll
    for (int fn = 0; fn < 4; ++fn) {
      int row = wc * 64 + fn * 16 + rr;
      b0[fn] = *(const bf16x8*)&lb[row * 64 + ((g ^ (row & 7)) << 3)];
      b1[fn] = *(const bf16x8*)&lb[row * 64 + (((4 + g) ^ (row & 7)) << 3)];
    }
    __builtin_amdgcn_s_setprio(1);
#pragma unroll
    for (int fm = 0; fm < 8; ++fm)
#pragma unroll
      for (int fn = 0; fn < 4; ++fn)
        acc[fm][fn] = __builtin_amdgcn_mfma_f32_16x16x32_bf16(a0[fm], b0[fn], acc[fm][fn], 0, 0, 0);
    __builtin_amdgcn_s_setprio(0);
    // all ds_reads (incl. a1/b1) must land before any wave overwrites buf[cur]
    asm volatile("s_waitcnt lgkmcnt(0)" ::: "memory");
    __builtin_amdgcn_s_barrier();
    if (t < 6) STAGE(cur, t + 2);
    __builtin_amdgcn_s_setprio(1);
#pragma unroll
    for (int fm = 0; fm < 8; ++fm)
#pragma unroll
      for (int fn = 0; fn < 4; ++fn)
        acc[fm][fn] = __builtin_amdgcn_mfma_f32_16x16x32_bf16(a1[fm], b1[fn], acc[fm][fn], 0, 0, 0);
    __builtin_amdgcn_s_setprio(0);
    if (t < 7) {
      if (t < 6) asm volatile("s_waitcnt vmcnt(8)" ::: "memory");  // next tile landed; t+2 stays in flight
      else       asm volatile("s_waitcnt vmcnt(0)" ::: "memory");  // drain last tile
      __builtin_amdgcn_s_barrier();
    }
  }
#undef STAGE

  // epilogue: scatter q/k, transposed v
#pragma unroll
  for (int fm = 0; fm < 8; ++fm)
#pragma unroll
    for (int fn = 0; fn < 4; ++fn) {
      int gcol = tn0 + wc * 64 + fn * 16 + rr;
      int reg = gcol >> 9, c = gcol & 511, h = c >> 6, d = c & 63;
      float bb = bias[gcol];
      int grow0 = tm0 + wr * 128 + fm * 16 + g * 4;  // 4-aligned; PD%4==0
      int b = grow0 / PD, p0 = grow0 - b * PD;
      if (reg == 2) {
        u16 u0 = f2bf(acc[fm][fn][0] + bb);
        u16 u1 = f2bf(acc[fm][fn][1] + bb);
        u16 u2 = f2bf(acc[fm][fn][2] + bb);
        u16 u3 = f2bf(acc[fm][fn][3] + bb);
        *(uint2*)&vt[(((size_t)(b * NH + h)) * HD + d) * PD + p0] =
            make_uint2((u32)u0 | ((u32)u1 << 16), (u32)u2 | ((u32)u3 << 16));
      } else if (reg == 1) {
#pragma unroll
        for (int r = 0; r < 4; ++r)
          kh[(((size_t)(b * NH + h)) * PD + p0 + r) * HD + d] = f2bf(acc[fm][fn][r] + bb);
      } else {
#pragma unroll
        for (int r = 0; r < 4; ++r) {
          int p = p0 + r;
          if (p >= OV && p < OV + SEQ)
            qh[(((size_t)(b * NH + h)) * SEQ + (p - OV)) * HD + d] = f2bf(acc[fm][fn][r] + bb);
        }
      }
    }
}

// ---------------- out-proj GEMM (unchanged 128x128 2-phase) ----------------
__device__ __forceinline__ void gemm_loop(const u16* __restrict__ A,
                                          const u16* __restrict__ Bw,
                                          int tm0, int tn0,
                                          u16* As, u16* Bs,
                                          f32x4 acc[4][4]) {
  const int tid = threadIdx.x;
  const int lane = tid & 63;
  const int w = tid >> 6;
  const int rr = lane & 15;
  const int kb = (lane >> 4) * 8;
  const int wm = (w >> 1) * 64, wn = (w & 1) * 64;
  const u16* gA = A + (size_t)(tm0 + w * 32 + (lane >> 2)) * 512 + (lane & 3) * 8;
  const u16* gB = Bw + (size_t)(tn0 + w * 32 + (lane >> 2)) * 512 + (lane & 3) * 8;
  char* lA = (char*)As + w * 2048;
  char* lB = (char*)Bs + w * 2048;

  GLL(gA, lA); GLL(gA + 16 * 512, lA + 1024);
  GLL(gB, lB); GLL(gB + 16 * 512, lB + 1024);
  __syncthreads();

#pragma unroll
  for (int t = 0; t < 16; ++t) {
    const int cur = t & 1;
    if (t < 15) {
      const int nxt = cur ^ 1;
      const u16* ga = gA + (t + 1) * 32;
      const u16* gb = gB + (t + 1) * 32;
      GLL(ga, lA + nxt * 8192); GLL(ga + 16 * 512, lA + nxt * 8192 + 1024);
      GLL(gb, lB + nxt * 8192); GLL(gb + 16 * 512, lB + nxt * 8192 + 1024);
    }
    const u16* cA = As + cur * 4096;
    const u16* cB = Bs + cur * 4096;
    bf16x8 af[4], bfr[4];
#pragma unroll
    for (int f = 0; f < 4; ++f) {
      af[f] = *(const bf16x8*)&cA[(wm + f * 16 + rr) * 32 + kb];
      bfr[f] = *(const bf16x8*)&cB[(wn + f * 16 + rr) * 32 + kb];
    }
#pragma unroll
    for (int fm = 0; fm < 4; ++fm)
#pragma unroll
      for (int fn = 0; fn < 4; ++fn)
        acc[fm][fn] = __builtin_amdgcn_mfma_f32_16x16x32_bf16(af[fm], bfr[fn], acc[fm][fn], 0, 0, 0);
    if (t < 15) __syncthreads();
  }
}

__global__ __launch_bounds__(256) void k_gemm_oproj(const u16* __restrict__ A,
                                                    const u16* __restrict__ Bw,
                                                    const float* __restrict__ bias,
                                                    const float* __restrict__ mainp,
                                                    float* __restrict__ out) {
  __shared__ __align__(16) u16 As[2][128][32];
  __shared__ __align__(16) u16 Bs[2][128][32];
  int bx = blockIdx.x;
  int tm0 = (bx >> 2) * 128, tn0 = (bx & 3) * 128;
  for (int i = threadIdx.x; i < 4096; i += 256) {
    int r = i >> 5, c4 = (i & 31) * 4;
    *(float4*)&out[(size_t)(tm0 + r) * 1024 + tn0 + c4] =
        *(const float4*)&mainp[(size_t)(tm0 + r) * 512 + tn0 + c4];
  }
  f32x4 acc[4][4] = {};
  gemm_loop(A, Bw, tm0, tn0, &As[0][0][0], &Bs[0][0][0], acc);
  int lane = threadIdx.x & 63, wv = threadIdx.x >> 6;
  int wm = (wv >> 1) * 64, wn = (wv & 1) * 64;
#pragma unroll
  for (int fm = 0; fm < 4; ++fm)
#pragma unroll
    for (int fn = 0; fn < 4; ++fn) {
      int j = tn0 + wn + fn * 16 + (lane & 15);
      float bb = bias[j];
#pragma unroll
      for (int r = 0; r < 4; ++r) {
        int row = tm0 + wm + fm * 16 + (lane >> 4) * 4 + r;
        out[(size_t)row * 1024 + 512 + j] = acc[fm][fn][r] + bb;
      }
    }
}

// ---------------- MFMA banded attention (unchanged) ----------------
__device__ __forceinline__ int pswz(int slot, int key) {
  return (slot < 8) ? (slot ^ (key & 7)) : ((slot & 12) | ((slot ^ (key & 3)) & 3));
}

__global__ __launch_bounds__(256) void k_attn(const u16* __restrict__ qh,
                                              const u16* __restrict__ kh,
                                              const u16* __restrict__ vt,
                                              u16* __restrict__ ob) {
  __shared__ __align__(16) u16 Ks[128 * 64];
  __shared__ __align__(16) u16 Vs[64 * 128];
  __shared__ __align__(16) u16 Qs[64 * 64];
  __shared__ __align__(16) u16 Ps[4 * 16 * 96];
  const int tid = threadIdx.x;
  const int lane = tid & 63;
  const int wq = tid >> 6;
  const int g = lane >> 4, qi = lane & 15;
  const int bx = blockIdx.x;
  const int tile = bx & 31, h = (bx >> 5) & 7, b = bx >> 8;
  const int l0 = tile * 64;
  const size_t bh = (size_t)(b * NH + h);

  {
    const u16* kg = kh + (bh * PD + l0) * HD;
#pragma unroll
    for (int i = 0; i < 4; ++i) {
      int c = tid + 256 * i;
      int row = c >> 3, slot = c & 7;
      *(uint4*)&Ks[row * 64 + ((slot ^ (row & 7)) << 3)] =
          *(const uint4*)&kg[(size_t)row * HD + slot * 8];
    }
    const u16* vg = vt + bh * HD * PD + l0;
#pragma unroll
    for (int i = 0; i < 4; ++i) {
      int c = tid + 256 * i;
      int d = c >> 4, slot = c & 15;
      *(uint4*)&Vs[d * 128 + ((slot ^ (d & 15)) << 3)] =
          *(const uint4*)&vg[(size_t)d * PD + slot * 8];
    }
    const u16* qg = qh + (bh * SEQ + l0) * HD;
#pragma unroll
    for (int i = 0; i < 2; ++i) {
      int c = tid + 256 * i;
      int row = c >> 3, slot = c & 7;
      *(uint4*)&Qs[row * 64 + ((slot ^ (row & 7)) << 3)] =
          *(const uint4*)&qg[(size_t)row * HD + slot * 8];
    }
  }
  __syncthreads();

  bf16x8 bq[2];
  {
    int qrow = 16 * wq + qi;
#pragma unroll
    for (int ks = 0; ks < 2; ++ks)
      bq[ks] = *(const bf16x8*)&Qs[qrow * 64 + ((((g + 4 * ks)) ^ (qrow & 7)) << 3)];
  }
  f32x4 sa[5];
#pragma unroll
  for (int tt = 0; tt < 5; ++tt) { f32x4 z = {0.f, 0.f, 0.f, 0.f}; sa[tt] = z; }
#pragma unroll
  for (int tt = 0; tt < 5; ++tt) {
    int krow = 16 * (wq + tt) + qi;
#pragma unroll
    for (int ks = 0; ks < 2; ++ks) {
      bf16x8 ak = *(const bf16x8*)&Ks[krow * 64 + (((g + 4 * ks) ^ (krow & 7)) << 3)];
      sa[tt] = __builtin_amdgcn_mfma_f32_16x16x32_bf16(ak, bq[ks], sa[tt], 0, 0, 0);
    }
  }

  float m = -1e30f;
#pragma unroll
  for (int tt = 0; tt < 5; ++tt)
#pragma unroll
    for (int r = 0; r < 4; ++r) {
      int rel = 16 * tt + 4 * g + r - qi;
      bool val = (rel >= 0) && (rel <= 64) && (rel != 32) && ((rel & 1) == 0);
      if (val) m = fmaxf(m, sa[tt][r]);
    }
  m = fmaxf(m, __shfl_xor(m, 16));
  m = fmaxf(m, __shfl_xor(m, 32));
  float p[5][4];
  float sum = 0.f;
#pragma unroll
  for (int tt = 0; tt < 5; ++tt)
#pragma unroll
    for (int r = 0; r < 4; ++r) {
      int rel = 16 * tt + 4 * g + r - qi;
      bool val = (rel >= 0) && (rel <= 64) && (rel != 32) && ((rel & 1) == 0);
      p[tt][r] = val ? __expf((sa[tt][r] - m) * 0.125f) : 0.f;
      sum += p[tt][r];
    }
  sum += __shfl_xor(sum, 16);
  sum += __shfl_xor(sum, 32);
  float inv = 1.f / sum;

  {
    int prow = 16 * wq + qi;
    int colb = (wq & 1) << 4;
#pragma unroll
    for (int tt = 0; tt < 5; ++tt) {
#pragma unroll
      for (int pp = 0; pp < 2; ++pp) {
        int e = 4 * g + 2 * pp;
        int slot = ((colb + 16 * tt) >> 3) + (e >> 3);
        int swz = pswz(slot, qi);
        u32 w = (u32)f2bf(p[tt][2 * pp] * inv) | ((u32)f2bf(p[tt][2 * pp + 1] * inv) << 16);
        *(u32*)&Ps[prow * 96 + swz * 8 + (e & 7)] = w;
      }
    }
    int zslot = ((wq & 1) ? 0 : 10) + ((lane >> 4) & 1);
    int half = lane >> 5;
    int swz = pswz(zslot, qi);
    uint2 z2 = make_uint2(0u, 0u);
    *(uint2*)&Ps[(16 * wq + qi) * 96 + swz * 8 + half * 4] = z2;
  }
  __syncthreads();

  f32x4 oa[4];
#pragma unroll
  for (int dt = 0; dt < 4; ++dt) { f32x4 z = {0.f, 0.f, 0.f, 0.f}; oa[dt] = z; }
  int kbo = (wq >= 2) ? 1 : 0;
#pragma unroll
  for (int kt = 0; kt < 3; ++kt) {
    int slot = 4 * kt + g;
    int swz = pswz(slot, qi);
    bf16x8 pa = *(const bf16x8*)&Ps[(16 * wq + qi) * 96 + swz * 8];
    int sabs = 4 * (kt + kbo) + g;
#pragma unroll
    for (int dt = 0; dt < 4; ++dt) {
      int d = 16 * dt + qi;
      bf16x8 bv = *(const bf16x8*)&Vs[d * 128 + ((sabs ^ (d & 15)) << 3)];
      oa[dt] = __builtin_amdgcn_mfma_f32_16x16x32_bf16(pa, bv, oa[dt], 0, 0, 0);
    }
  }

  u16* og = ob + ((size_t)b * SEQ + l0 + 16 * wq) * DIM + h * HD;
#pragma unroll
  for (int dt = 0; dt < 4; ++dt)
#pragma unroll
    for (int r = 0; r < 4; ++r) {
      int qo = 4 * g + r;
      og[(size_t)qo * DIM + 16 * dt + qi] = f2bf(oa[dt][r]);
    }
}

extern "C" void kernel_launch(void* const* d_in, const int* in_sizes, int n_in,
                              void* d_out, int out_size, void* d_ws, size_t ws_size,
                              hipStream_t stream) {
  const float* begin = (const float*)d_in[0];
  const float* mainp = (const float*)d_in[1];
  const float* endp = (const float*)d_in[2];
  const float* w_in_f = (const float*)d_in[3];
  const float* b_in = (const float*)d_in[4];
  const float* w_out_f = (const float*)d_in[5];
  const float* b_out = (const float*)d_in[6];
  float* out = (float*)d_out;

  char* ws = (char*)d_ws;
  u16* pad_bf = (u16*)ws; ws += (size_t)NB * PD * DIM * 2;
  u16* w_in = (u16*)ws;   ws += (size_t)3 * DIM * DIM * 2;
  u16* w_out = (u16*)ws;  ws += (size_t)DIM * DIM * 2;
  u16* qhb = (u16*)ws;    ws += (size_t)NB * NH * SEQ * HD * 2;
  u16* khb = (u16*)ws;    ws += (size_t)NB * NH * PD * HD * 2;
  u16* vtb = (u16*)ws;    ws += (size_t)NB * NH * HD * PD * 2;
  u16* ob = (u16*)ws;     ws += (size_t)NB * SEQ * DIM * 2;

  k_prep<<<(PACK_N + WIN_N + WOUT_N + 255) / 256, 256, 0, stream>>>(
      begin, mainp, endp, w_in_f, w_out_f, pad_bf, w_in, w_out);
  k_gemm_qkv<<<33 * 6, 512, 0, stream>>>(pad_bf, w_in, b_in, qhb, khb, vtb);
  k_attn<<<NB * NH * (SEQ / 64), 256, 0, stream>>>(qhb, khb, vtb, ob);
  k_gemm_oproj<<<64 * 4, 256, 0, stream>>>(ob, w_out, b_out, mainp, out);
}